// Round 5
// baseline (405.631 us; speedup 1.0000x reference)
//
#include <hip/hip_runtime.h>

typedef unsigned int uint;
typedef unsigned short ushort;
typedef __bf16 bf16x8 __attribute__((ext_vector_type(8)));
typedef float f32x4 __attribute__((ext_vector_type(4)));
typedef uint u32x4 __attribute__((ext_vector_type(4)));

#define DEV static __device__ __forceinline__

#define BATCH 2
#define SEQ 2048
#define DMODEL 2048
#define NHEADS 16
#define DHEAD 128
#define MROWS (BATCH*SEQ)           // 4096
#define RSCALE 0.08838834764831845f // 1/sqrt(128)
#define LOG2E  1.4426950408889634f

DEV float fast_exp2(float x) { return __builtin_amdgcn_exp2f(x); }

DEV bf16x8 as_frag(u32x4 v) { return __builtin_bit_cast(bf16x8, v); }
DEV ushort f2bf(float f) {
  uint u = __builtin_bit_cast(uint, f);
  u += 0x7fffu + ((u >> 16) & 1u);   // RNE
  return (ushort)(u >> 16);
}
DEV u32x4 lds_ld16(const ushort* p) { return *(const u32x4*)p; }

// async global->LDS, 16B per lane; LDS dest = wave-uniform base + lane*16
DEV void async_cp16(const ushort* g, ushort* l) {
  __builtin_amdgcn_global_load_lds(
      (const __attribute__((address_space(1))) uint*)g,
      (__attribute__((address_space(3))) uint*)l, 16, 0, 0);
}

// ---------------------------------------------------------------------------
// Fused preprocessing: x f32->bf16 convert + 4 weight transposes (f32->bf16)
// block ranges: [0,8192) convert; [8192,20480) Wq/Wk/Wv T; [20480,24576) Wo T
// ---------------------------------------------------------------------------
__global__ __launch_bounds__(256) void prep(
    const float* __restrict__ x,
    const float* __restrict__ Wq, const float* __restrict__ Wk,
    const float* __restrict__ Wv, const float* __restrict__ Wo,
    ushort* __restrict__ xb, ushort* __restrict__ WqT,
    ushort* __restrict__ WkT, ushort* __restrict__ WvT,
    ushort* __restrict__ WoT)
{
  int id = blockIdx.x;
  if (id < 8192) {
    int i = id * 256 + threadIdx.x;       // n4 = 2,097,152 exactly
    float4 v = ((const float4*)x)[i];
    union { ushort u[4]; uint2 w; } o;
    o.u[0] = f2bf(v.x); o.u[1] = f2bf(v.y); o.u[2] = f2bf(v.z); o.u[3] = f2bf(v.w);
    ((uint2*)xb)[i] = o.w;
    return;
  }
  __shared__ ushort t[32][33];
  id -= 8192;
  const float* src; ushort* dst; int R, C, c0, r0;
  if (id < 12288) {
    int which = id >> 12;                 // /4096
    int r = id & 4095;
    int slice = r >> 8;
    int rem = r & 255;
    int ty = rem >> 2, tx = rem & 3;
    const float* S[3] = {Wq, Wk, Wv};
    ushort* D[3] = {WqT, WkT, WvT};
    src = S[which] + (size_t)slice * DMODEL * DHEAD;
    dst = D[which] + (size_t)slice * DMODEL * DHEAD;
    R = DMODEL; C = DHEAD; c0 = tx * 32; r0 = ty * 32;
  } else {
    id -= 12288;
    int tx = id & 63, ty = id >> 6;
    src = Wo; dst = WoT; R = DMODEL; C = DMODEL; c0 = tx * 32; r0 = ty * 32;
  }
  int xx = threadIdx.x & 31, yy = threadIdx.x >> 5;
  #pragma unroll
  for (int i = 0; i < 32; i += 8)
    t[yy + i][xx] = f2bf(src[(size_t)(r0 + yy + i) * C + (c0 + xx)]);
  __syncthreads();
  #pragma unroll
  for (int i = 0; i < 32; i += 8)
    dst[(size_t)(c0 + yy + i) * R + (r0 + xx)] = t[xx][yy + i];
}

// ---------------------------------------------------------------------------
// QKV projection GEMM (m97-style, round-0 body). Q pre-scaled by RSCALE*LOG2E
// (exp2 domain); V written transposed Vt[bh][e][pos].
// Round-5: T1 XCD-aware chunked block swizzle only. 1536 blocks = 8 XCDs x 192
// consecutive ids -> each XCD sees 6 full (h,which) B-panels (3 MB, fits 4 MB
// L2) + ~4 concurrent readers per A-tile. Shortens the staging-load latency
// that the per-K-step __syncthreads drain waits on.
// ---------------------------------------------------------------------------
__global__ __launch_bounds__(256, 4) void gemm_qkv(
    const ushort* __restrict__ xb,
    const ushort* __restrict__ WqT, const ushort* __restrict__ WkT,
    const ushort* __restrict__ WvT,
    const float* __restrict__ bQ, const float* __restrict__ bK,
    const float* __restrict__ bV,
    ushort* __restrict__ Qo, ushort* __restrict__ Ko, ushort* __restrict__ Vt)
{
  // bijective chunked XCD swizzle: 1536 = 8 * 192
  int id = blockIdx.x + 32 * blockIdx.y + 512 * blockIdx.z;
  int swz = (id & 7) * 192 + (id >> 3);
  int which = swz >> 9;          // 0:Q 1:K 2:V
  int rem = swz & 511;
  int h  = rem >> 5;             // 0..15
  int mt = rem & 31;             // 0..31

  const ushort* Bt = (which == 0) ? WqT : (which == 1) ? WkT : WvT;
  const float* bias = (which == 0) ? bQ : (which == 1) ? bK : bV;
  Bt += (size_t)h * DHEAD * DMODEL;
  bias += h * DHEAD;

  __shared__ __align__(16) ushort As[128 * 64];
  __shared__ __align__(16) ushort Bs[128 * 64];

  int tid = threadIdx.x, lane = tid & 63, w = tid >> 6;
  int wm = w >> 1, wn = w & 1;
  int l16 = lane & 15, quad = lane >> 4;

  const ushort* Ag = xb + (size_t)(mt * 128) * DMODEL;

  int soff[4]; int sc[4];
  #pragma unroll
  for (int t = 0; t < 4; t++) {
    int c = w * 4 + t;
    int r = c * 8 + (lane >> 3);
    int p = lane & 7;
    int g = p ^ (r & 7);
    soff[t] = r * DMODEL + g * 8;
    sc[t] = c * 512;
  }

  f32x4 acc[4][4] = {};

  for (int k0 = 0; k0 < DMODEL; k0 += 64) {
    __syncthreads();
    #pragma unroll
    for (int t = 0; t < 4; t++) {
      async_cp16(Ag + soff[t] + k0, As + sc[t]);
      async_cp16(Bt + soff[t] + k0, Bs + sc[t]);
    }
    __syncthreads();
    #pragma unroll
    for (int kk = 0; kk < 2; kk++) {
      bf16x8 a[4], b[4];
      #pragma unroll
      for (int i = 0; i < 4; i++) {
        int row = wm * 64 + i * 16 + l16;
        int p = (kk * 4 + quad) ^ (l16 & 7);
        a[i] = as_frag(lds_ld16(As + row * 64 + p * 8));
      }
      #pragma unroll
      for (int i = 0; i < 4; i++) {
        int row = wn * 64 + i * 16 + l16;
        int p = (kk * 4 + quad) ^ (l16 & 7);
        b[i] = as_frag(lds_ld16(Bs + row * 64 + p * 8));
      }
      #pragma unroll
      for (int i = 0; i < 4; i++)
        #pragma unroll
        for (int j = 0; j < 4; j++)
          acc[i][j] = __builtin_amdgcn_mfma_f32_16x16x32_bf16(a[i], b[j], acc[i][j], 0, 0, 0);
    }
  }

  float scale = (which == 0) ? RSCALE * LOG2E : 1.0f;
  #pragma unroll
  for (int i = 0; i < 4; i++) {
    #pragma unroll
    for (int j = 0; j < 4; j++) {
      int col = wn * 64 + j * 16 + l16;       // e
      float bb = bias[col];
      #pragma unroll
      for (int r = 0; r < 4; r++) {
        int row = mt * 128 + wm * 64 + i * 16 + quad * 4 + r;
        int b_ = row >> 11, p = row & 2047;
        int bh = b_ * NHEADS + h;
        ushort val = f2bf((acc[i][j][r] + bb) * scale);
        if (which == 2) {
          Vt[((size_t)bh * DHEAD + col) * SEQ + p] = val;
        } else {
          ushort* Out = (which == 0) ? Qo : Ko;
          Out[((size_t)bh * SEQ + p) * DHEAD + col] = val;
        }
      }
    }
  }
}

// ---------------------------------------------------------------------------
// Flash attention (causal), 1 barrier/chunk: K/V double-buffered async
// staging overlaps compute; Ps is wave-private (no barrier). exp2 domain.
// Block a does qtiles {31-a, a}; 512 blocks, 2 blocks/CU.
// Round-5: T1 chunked XCD swizzle — 16 a-blocks sharing one bh's K/V land on
// the same XCD (4 bh x 1 MB K/V ~ L2-resident).
// ---------------------------------------------------------------------------
__global__ __launch_bounds__(256, 2) void flash_attn(
    const ushort* __restrict__ Q, const ushort* __restrict__ K,
    const ushort* __restrict__ Vt, ushort* __restrict__ Z)
{
  // bijective chunked XCD swizzle: 512 = 8 * 64
  int id = blockIdx.x + 16 * blockIdx.y;
  int swz = (id & 7) * 64 + (id >> 3);
  int a  = swz & 15;     // 0..15
  int bh = swz >> 4;     // 0..31
  const ushort* Qg = Q + (size_t)bh * SEQ * DHEAD;   // [2048][128]
  const ushort* Kg = K + (size_t)bh * SEQ * DHEAD;
  const ushort* Vg = Vt + (size_t)bh * DHEAD * SEQ;  // [128][2048]

  __shared__ __align__(16) ushort Ks[2][64 * 128];   // 32 KB
  __shared__ __align__(16) ushort Vs[2][128 * 64];   // 32 KB
  __shared__ __align__(16) ushort Ps[64 * 72];       // 9 KB (wave-private rows)

  int tid = threadIdx.x, lane = tid & 63, w = tid >> 6;
  int l16 = lane & 15, quad = lane >> 4;

  int kOff[4], vOff[4], cLds[4];
  #pragma unroll
  for (int t = 0; t < 4; t++) {
    int c = w * 4 + t;
    cLds[t] = c * 512;
    int rk = c * 4 + (lane >> 4);
    int pk = lane & 15;
    int gk = (pk & 8) | ((pk & 7) ^ (rk & 7));
    kOff[t] = rk * DHEAD + gk * 8;
    int ev = c * 8 + (lane >> 3);
    int pv = lane & 7;
    int gv = pv ^ (ev & 7);
    vOff[t] = ev * SEQ + gv * 8;
  }

  #pragma unroll
  for (int ph = 0; ph < 2; ph++) {
    int qt = ph ? a : (31 - a);
    int q0 = qt * 64;

    bf16x8 qf[4];
    int qrow = q0 + w * 16 + l16;
    #pragma unroll
    for (int kb = 0; kb < 4; kb++)
      qf[kb] = as_frag(*(const u32x4*)(Qg + qrow * DHEAD + kb * 32 + quad * 8));

    float m_i[4], l_i[4];
    #pragma unroll
    for (int i = 0; i < 4; i++) { m_i[i] = -1e30f; l_i[i] = 0.0f; }
    f32x4 zacc[8] = {};

    // prologue: stage chunk 0 into buffer 0
    #pragma unroll
    for (int t = 0; t < 4; t++) {
      async_cp16(Kg + kOff[t], Ks[0] + cLds[t]);
      async_cp16(Vg + vOff[t], Vs[0] + cLds[t]);
    }
    __syncthreads();   // staging 0 visible (vmcnt drained)

    for (int j = 0; j <= qt; j++) {
      int cur = j & 1;
      // issue async staging for chunk j+1 — overlaps this chunk's compute
      if (j < qt) {
        int k1 = (j + 1) * 64;
        #pragma unroll
        for (int t = 0; t < 4; t++) {
          async_cp16(Kg + k1 * DHEAD + kOff[t], Ks[cur ^ 1] + cLds[t]);
          async_cp16(Vg + k1 + vOff[t], Vs[cur ^ 1] + cLds[t]);
        }
      }
      const ushort* KsC = Ks[cur];
      const ushort* VsC = Vs[cur];

      // S = Q K^T
      f32x4 s[4] = {};
      #pragma unroll
      for (int kb = 0; kb < 4; kb++) {
        #pragma unroll
        for (int n = 0; n < 4; n++) {
          int r = n * 16 + l16;
          int ug = kb * 4 + quad;
          int p = (ug & 8) | ((ug & 7) ^ (r & 7));
          bf16x8 b = as_frag(lds_ld16(KsC + r * 128 + p * 8));
          s[n] = __builtin_amdgcn_mfma_f32_16x16x32_bf16(qf[kb], b, s[n], 0, 0, 0);
        }
      }
      // causal mask on diagonal chunk only (s already in exp2 domain)
      if (j == qt) {
        #pragma unroll
        for (int n = 0; n < 4; n++)
          #pragma unroll
          for (int i = 0; i < 4; i++) {
            int qr = 16 * w + quad * 4 + i;
            int kr = n * 16 + l16;
            if (kr > qr) s[n][i] = -1e30f;
          }
      }
      float mx[4];
      #pragma unroll
      for (int i = 0; i < 4; i++)
        mx[i] = fmaxf(fmaxf(s[0][i], s[1][i]), fmaxf(s[2][i], s[3][i]));
      #pragma unroll
      for (int off = 1; off < 16; off <<= 1)
        #pragma unroll
        for (int i = 0; i < 4; i++)
          mx[i] = fmaxf(mx[i], __shfl_xor(mx[i], off, 64));

      float alpha[4], rsum[4];
      #pragma unroll
      for (int i = 0; i < 4; i++) {
        float mn = fmaxf(m_i[i], mx[i]);
        alpha[i] = fast_exp2(m_i[i] - mn);
        m_i[i] = mn;
        rsum[i] = 0.0f;
      }
      #pragma unroll
      for (int n = 0; n < 4; n++)
        #pragma unroll
        for (int i = 0; i < 4; i++) {
          float p = fast_exp2(s[n][i] - m_i[i]);
          rsum[i] += p;
          int row = 16 * w + quad * 4 + i, col = n * 16 + l16;
          Ps[row * 72 + col] = f2bf(p);
        }
      #pragma unroll
      for (int off = 1; off < 16; off <<= 1)
        #pragma unroll
        for (int i = 0; i < 4; i++)
          rsum[i] += __shfl_xor(rsum[i], off, 64);
      #pragma unroll
      for (int i = 0; i < 4; i++) l_i[i] = l_i[i] * alpha[i] + rsum[i];
      #pragma unroll
      for (int n = 0; n < 8; n++)
        #pragma unroll
        for (int i = 0; i < 4; i++) zacc[n][i] *= alpha[i];

      // O += P V  (Ps rows are wave-private: compiler's lgkmcnt handles WAR)
      #pragma unroll
      for (int kk = 0; kk < 2; kk++) {
        bf16x8 af = as_frag(lds_ld16(Ps + (w * 16 + l16) * 72 + (kk * 4 + quad) * 8));
        #pragma unroll
        for (int n = 0; n < 8; n++) {
          int e = n * 16 + l16;
          int ug = kk * 4 + quad;
          int p = ug ^ (e & 7);
          bf16x8 b = as_frag(lds_ld16(VsC + e * 64 + p * 8));
          zacc[n] = __builtin_amdgcn_mfma_f32_16x16x32_bf16(af, b, zacc[n], 0, 0, 0);
        }
      }
      __syncthreads();   // reads of buf[cur] done; staging j+1 drained
    }

    // epilogue: Z[b*2048+pos][h*128+e] = zacc / l  (bf16)
    int b_ = bh >> 4, h = bh & 15;
    #pragma unroll
    for (int n = 0; n < 8; n++)
      #pragma unroll
      for (int i = 0; i < 4; i++) {
        int row = q0 + 16 * w + quad * 4 + i;
        int col = h * DHEAD + n * 16 + l16;
        Z[((size_t)(b_ * SEQ + row)) * DMODEL + col] = f2bf(zacc[n][i] / l_i[i]);
      }
  }
}

// ---------------------------------------------------------------------------
// Output projection (m97-style): out f32 = Z bf16 * WoT + bO  (control: no swz)
// ---------------------------------------------------------------------------
__global__ __launch_bounds__(256, 4) void gemm_out(
    const ushort* __restrict__ Zin, const ushort* __restrict__ WoT,
    const float* __restrict__ bO, float* __restrict__ out)
{
  int mt = blockIdx.x, ntile = blockIdx.y;
  __shared__ __align__(16) ushort As[128 * 64];
  __shared__ __align__(16) ushort Bs[128 * 64];
  int tid = threadIdx.x, lane = tid & 63, w = tid >> 6;
  int wm = w >> 1, wn = w & 1;
  int l16 = lane & 15, quad = lane >> 4;

  const ushort* Ag = Zin + (size_t)(mt * 128) * DMODEL;
  const ushort* Bg = WoT + (size_t)(ntile * 128) * DMODEL;

  int soff[4]; int sc[4];
  #pragma unroll
  for (int t = 0; t < 4; t++) {
    int c = w * 4 + t;
    int r = c * 8 + (lane >> 3);
    int p = lane & 7;
    int g = p ^ (r & 7);
    soff[t] = r * DMODEL + g * 8;
    sc[t] = c * 512;
  }

  f32x4 acc[4][4] = {};
  for (int k0 = 0; k0 < DMODEL; k0 += 64) {
    __syncthreads();
    #pragma unroll
    for (int t = 0; t < 4; t++) {
      async_cp16(Ag + soff[t] + k0, As + sc[t]);
      async_cp16(Bg + soff[t] + k0, Bs + sc[t]);
    }
    __syncthreads();
    #pragma unroll
    for (int kk = 0; kk < 2; kk++) {
      bf16x8 a[4], b[4];
      #pragma unroll
      for (int i = 0; i < 4; i++) {
        int row = wm * 64 + i * 16 + l16;
        int p = (kk * 4 + quad) ^ (l16 & 7);
        a[i] = as_frag(lds_ld16(As + row * 64 + p * 8));
      }
      #pragma unroll
      for (int i = 0; i < 4; i++) {
        int row = wn * 64 + i * 16 + l16;
        int p = (kk * 4 + quad) ^ (l16 & 7);
        b[i] = as_frag(lds_ld16(Bs + row * 64 + p * 8));
      }
      #pragma unroll
      for (int i = 0; i < 4; i++)
        #pragma unroll
        for (int j = 0; j < 4; j++)
          acc[i][j] = __builtin_amdgcn_mfma_f32_16x16x32_bf16(a[i], b[j], acc[i][j], 0, 0, 0);
    }
  }
  #pragma unroll
  for (int i = 0; i < 4; i++) {
    #pragma unroll
    for (int j = 0; j < 4; j++) {
      int col = ntile * 128 + wn * 64 + j * 16 + l16;
      float bb = bO[col];
      #pragma unroll
      for (int r = 0; r < 4; r++) {
        int row = mt * 128 + wm * 64 + i * 16 + quad * 4 + r;
        out[(size_t)row * DMODEL + col] = acc[i][j][r] + bb;
      }
    }
  }
}

// ---------------------------------------------------------------------------
extern "C" void kernel_launch(void* const* d_in, const int* in_sizes, int n_in,
                              void* d_out, int out_size, void* d_ws, size_t ws_size,
                              hipStream_t stream)
{
  const float* x  = (const float*)d_in[0];
  const float* Wq = (const float*)d_in[1];
  const float* Wk = (const float*)d_in[2];
  const float* Wv = (const float*)d_in[3];
  const float* Wo = (const float*)d_in[4];
  const float* bQ = (const float*)d_in[5];
  const float* bK = (const float*)d_in[6];
  const float* bV = (const float*)d_in[7];
  const float* bO = (const float*)d_in[8];
  float* out = (float*)d_out;

  ushort* ws = (ushort*)d_ws;
  const size_t WSZ = (size_t)NHEADS * DHEAD * DMODEL;       // 4,194,304
  const size_t QSZ = (size_t)BATCH * NHEADS * SEQ * DHEAD;  // 8,388,608
  ushort* xb  = ws;
  ushort* WqT = xb + (size_t)MROWS * DMODEL;
  ushort* WkT = WqT + WSZ;
  ushort* WvT = WkT + WSZ;
  ushort* WoT = WvT + WSZ;
  ushort* Qb  = WoT + (size_t)DMODEL * DMODEL;
  ushort* Kb  = Qb + QSZ;
  ushort* VtB = Kb + QSZ;
  ushort* Zb  = VtB + QSZ;

  dim3 tb(256);
  prep<<<dim3(24576), tb, 0, stream>>>(x, Wq, Wk, Wv, Wo,
                                       xb, WqT, WkT, WvT, WoT);

  gemm_qkv<<<dim3(32, 16, 3), tb, 0, stream>>>(xb, WqT, WkT, WvT, bQ, bK, bV,
                                               Qb, Kb, VtB);

  flash_attn<<<dim3(16, 32), tb, 0, stream>>>(Qb, Kb, VtB, Zb);

  gemm_out<<<dim3(32, 16), tb, 0, stream>>>(Zb, WoT, bO, out);
}

// Round 6
// 394.761 us; speedup vs baseline: 1.0275x; 1.0275x over previous
//
#include <hip/hip_runtime.h>

typedef unsigned int uint;
typedef unsigned short ushort;
typedef __bf16 bf16x8 __attribute__((ext_vector_type(8)));
typedef float f32x4 __attribute__((ext_vector_type(4)));
typedef uint u32x4 __attribute__((ext_vector_type(4)));

#define DEV static __device__ __forceinline__

#define BATCH 2
#define SEQ 2048
#define DMODEL 2048
#define NHEADS 16
#define DHEAD 128
#define MROWS (BATCH*SEQ)           // 4096
#define RSCALE 0.08838834764831845f // 1/sqrt(128)
#define LOG2E  1.4426950408889634f

DEV float fast_exp2(float x) { return __builtin_amdgcn_exp2f(x); }

DEV bf16x8 as_frag(u32x4 v) { return __builtin_bit_cast(bf16x8, v); }
DEV ushort f2bf(float f) {
  uint u = __builtin_bit_cast(uint, f);
  u += 0x7fffu + ((u >> 16) & 1u);   // RNE
  return (ushort)(u >> 16);
}
DEV u32x4 lds_ld16(const ushort* p) { return *(const u32x4*)p; }

// async global->LDS, 16B per lane; LDS dest = wave-uniform base + lane*16
DEV void async_cp16(const ushort* g, ushort* l) {
  __builtin_amdgcn_global_load_lds(
      (const __attribute__((address_space(1))) uint*)g,
      (__attribute__((address_space(3))) uint*)l, 16, 0, 0);
}

// ---------------------------------------------------------------------------
// Fused preprocessing: x f32->bf16 convert + 4 weight transposes (f32->bf16)
// block ranges: [0,2048) convert (4 float4/thread); [2048,14336) Wq/Wk/Wv T;
// [14336,18432) Wo T
// ---------------------------------------------------------------------------
__global__ __launch_bounds__(256) void prep(
    const float* __restrict__ x,
    const float* __restrict__ Wq, const float* __restrict__ Wk,
    const float* __restrict__ Wv, const float* __restrict__ Wo,
    ushort* __restrict__ xb, ushort* __restrict__ WqT,
    ushort* __restrict__ WkT, ushort* __restrict__ WvT,
    ushort* __restrict__ WoT)
{
  int id = blockIdx.x;
  if (id < 2048) {
    // n4 = 2,097,152 float4 total = 2048 blocks * 256 threads * 4
    #pragma unroll
    for (int k = 0; k < 4; k++) {
      int i = id * 1024 + k * 256 + threadIdx.x;
      float4 v = ((const float4*)x)[i];
      union { ushort u[4]; uint2 w; } o;
      o.u[0] = f2bf(v.x); o.u[1] = f2bf(v.y); o.u[2] = f2bf(v.z); o.u[3] = f2bf(v.w);
      ((uint2*)xb)[i] = o.w;
    }
    return;
  }
  __shared__ ushort t[32][33];
  id -= 2048;
  const float* src; ushort* dst; int R, C, c0, r0;
  if (id < 12288) {
    int which = id >> 12;                 // /4096
    int r = id & 4095;
    int slice = r >> 8;
    int rem = r & 255;
    int ty = rem >> 2, tx = rem & 3;
    const float* S[3] = {Wq, Wk, Wv};
    ushort* D[3] = {WqT, WkT, WvT};
    src = S[which] + (size_t)slice * DMODEL * DHEAD;
    dst = D[which] + (size_t)slice * DMODEL * DHEAD;
    R = DMODEL; C = DHEAD; c0 = tx * 32; r0 = ty * 32;
  } else {
    id -= 12288;
    int tx = id & 63, ty = id >> 6;
    src = Wo; dst = WoT; R = DMODEL; C = DMODEL; c0 = tx * 32; r0 = ty * 32;
  }
  int xx = threadIdx.x & 31, yy = threadIdx.x >> 5;
  #pragma unroll
  for (int i = 0; i < 32; i += 8)
    t[yy + i][xx] = f2bf(src[(size_t)(r0 + yy + i) * C + (c0 + xx)]);
  __syncthreads();
  #pragma unroll
  for (int i = 0; i < 32; i += 8)
    dst[(size_t)(c0 + yy + i) * R + (r0 + xx)] = t[xx][yy + i];
}

// ---------------------------------------------------------------------------
// QKV projection GEMM (m97-style). Q pre-scaled by RSCALE*LOG2E (exp2 domain);
// V written transposed Vt[bh][e][pos].
// NOTE: default dispatch order already co-locates all readers of an A-tile
// on one XCD (id%8 == mt%8) — do NOT block-swizzle this grid (r5: FETCH 2x).
// ---------------------------------------------------------------------------
__global__ __launch_bounds__(256, 4) void gemm_qkv(
    const ushort* __restrict__ xb,
    const ushort* __restrict__ WqT, const ushort* __restrict__ WkT,
    const ushort* __restrict__ WvT,
    const float* __restrict__ bQ, const float* __restrict__ bK,
    const float* __restrict__ bV,
    ushort* __restrict__ Qo, ushort* __restrict__ Ko, ushort* __restrict__ Vt)
{
  int mt = blockIdx.x;       // 0..31
  int h  = blockIdx.y;       // 0..15
  int which = blockIdx.z;    // 0:Q 1:K 2:V
  const ushort* Bt = (which == 0) ? WqT : (which == 1) ? WkT : WvT;
  const float* bias = (which == 0) ? bQ : (which == 1) ? bK : bV;
  Bt += (size_t)h * DHEAD * DMODEL;
  bias += h * DHEAD;

  __shared__ __align__(16) ushort As[128 * 64];
  __shared__ __align__(16) ushort Bs[128 * 64];

  int tid = threadIdx.x, lane = tid & 63, w = tid >> 6;
  int wm = w >> 1, wn = w & 1;
  int l16 = lane & 15, quad = lane >> 4;

  const ushort* Ag = xb + (size_t)(mt * 128) * DMODEL;

  int soff[4]; int sc[4];
  #pragma unroll
  for (int t = 0; t < 4; t++) {
    int c = w * 4 + t;
    int r = c * 8 + (lane >> 3);
    int p = lane & 7;
    int g = p ^ (r & 7);
    soff[t] = r * DMODEL + g * 8;
    sc[t] = c * 512;
  }

  f32x4 acc[4][4] = {};

  for (int k0 = 0; k0 < DMODEL; k0 += 64) {
    __syncthreads();
    #pragma unroll
    for (int t = 0; t < 4; t++) {
      async_cp16(Ag + soff[t] + k0, As + sc[t]);
      async_cp16(Bt + soff[t] + k0, Bs + sc[t]);
    }
    __syncthreads();
    #pragma unroll
    for (int kk = 0; kk < 2; kk++) {
      bf16x8 a[4], b[4];
      #pragma unroll
      for (int i = 0; i < 4; i++) {
        int row = wm * 64 + i * 16 + l16;
        int p = (kk * 4 + quad) ^ (l16 & 7);
        a[i] = as_frag(lds_ld16(As + row * 64 + p * 8));
      }
      #pragma unroll
      for (int i = 0; i < 4; i++) {
        int row = wn * 64 + i * 16 + l16;
        int p = (kk * 4 + quad) ^ (l16 & 7);
        b[i] = as_frag(lds_ld16(Bs + row * 64 + p * 8));
      }
      #pragma unroll
      for (int i = 0; i < 4; i++)
        #pragma unroll
        for (int j = 0; j < 4; j++)
          acc[i][j] = __builtin_amdgcn_mfma_f32_16x16x32_bf16(a[i], b[j], acc[i][j], 0, 0, 0);
    }
  }

  float scale = (which == 0) ? RSCALE * LOG2E : 1.0f;
  #pragma unroll
  for (int i = 0; i < 4; i++) {
    #pragma unroll
    for (int j = 0; j < 4; j++) {
      int col = wn * 64 + j * 16 + l16;       // e
      float bb = bias[col];
      #pragma unroll
      for (int r = 0; r < 4; r++) {
        int row = mt * 128 + wm * 64 + i * 16 + quad * 4 + r;
        int b_ = row >> 11, p = row & 2047;
        int bh = b_ * NHEADS + h;
        ushort val = f2bf((acc[i][j][r] + bb) * scale);
        if (which == 2) {
          Vt[((size_t)bh * DHEAD + col) * SEQ + p] = val;
        } else {
          ushort* Out = (which == 0) ? Qo : Ko;
          Out[((size_t)bh * SEQ + p) * DHEAD + col] = val;
        }
      }
    }
  }
}

// ---------------------------------------------------------------------------
// Flash attention (causal), 1 barrier/chunk: K/V double-buffered async
// staging overlaps compute; Ps is wave-private (no barrier). exp2 domain.
// Block a does qtiles {31-a, a}; 512 blocks, 2 blocks/CU.
// (round-0 form; T5/T13 measured net-negative on this barrier-synced
//  structure in r3 — kept out; block swizzle measured negative in r5.)
// ---------------------------------------------------------------------------
__global__ __launch_bounds__(256, 2) void flash_attn(
    const ushort* __restrict__ Q, const ushort* __restrict__ K,
    const ushort* __restrict__ Vt, ushort* __restrict__ Z)
{
  int a  = blockIdx.x;   // 0..15
  int bh = blockIdx.y;   // 0..31
  const ushort* Qg = Q + (size_t)bh * SEQ * DHEAD;   // [2048][128]
  const ushort* Kg = K + (size_t)bh * SEQ * DHEAD;
  const ushort* Vg = Vt + (size_t)bh * DHEAD * SEQ;  // [128][2048]

  __shared__ __align__(16) ushort Ks[2][64 * 128];   // 32 KB
  __shared__ __align__(16) ushort Vs[2][128 * 64];   // 32 KB
  __shared__ __align__(16) ushort Ps[64 * 72];       // 9 KB (wave-private rows)

  int tid = threadIdx.x, lane = tid & 63, w = tid >> 6;
  int l16 = lane & 15, quad = lane >> 4;

  int kOff[4], vOff[4], cLds[4];
  #pragma unroll
  for (int t = 0; t < 4; t++) {
    int c = w * 4 + t;
    cLds[t] = c * 512;
    int rk = c * 4 + (lane >> 4);
    int pk = lane & 15;
    int gk = (pk & 8) | ((pk & 7) ^ (rk & 7));
    kOff[t] = rk * DHEAD + gk * 8;
    int ev = c * 8 + (lane >> 3);
    int pv = lane & 7;
    int gv = pv ^ (ev & 7);
    vOff[t] = ev * SEQ + gv * 8;
  }

  #pragma unroll
  for (int ph = 0; ph < 2; ph++) {
    int qt = ph ? a : (31 - a);
    int q0 = qt * 64;

    bf16x8 qf[4];
    int qrow = q0 + w * 16 + l16;
    #pragma unroll
    for (int kb = 0; kb < 4; kb++)
      qf[kb] = as_frag(*(const u32x4*)(Qg + qrow * DHEAD + kb * 32 + quad * 8));

    float m_i[4], l_i[4];
    #pragma unroll
    for (int i = 0; i < 4; i++) { m_i[i] = -1e30f; l_i[i] = 0.0f; }
    f32x4 zacc[8] = {};

    // prologue: stage chunk 0 into buffer 0
    #pragma unroll
    for (int t = 0; t < 4; t++) {
      async_cp16(Kg + kOff[t], Ks[0] + cLds[t]);
      async_cp16(Vg + vOff[t], Vs[0] + cLds[t]);
    }
    __syncthreads();   // staging 0 visible (vmcnt drained)

    for (int j = 0; j <= qt; j++) {
      int cur = j & 1;
      // issue async staging for chunk j+1 — overlaps this chunk's compute
      if (j < qt) {
        int k1 = (j + 1) * 64;
        #pragma unroll
        for (int t = 0; t < 4; t++) {
          async_cp16(Kg + k1 * DHEAD + kOff[t], Ks[cur ^ 1] + cLds[t]);
          async_cp16(Vg + k1 + vOff[t], Vs[cur ^ 1] + cLds[t]);
        }
      }
      const ushort* KsC = Ks[cur];
      const ushort* VsC = Vs[cur];

      // S = Q K^T
      f32x4 s[4] = {};
      #pragma unroll
      for (int kb = 0; kb < 4; kb++) {
        #pragma unroll
        for (int n = 0; n < 4; n++) {
          int r = n * 16 + l16;
          int ug = kb * 4 + quad;
          int p = (ug & 8) | ((ug & 7) ^ (r & 7));
          bf16x8 b = as_frag(lds_ld16(KsC + r * 128 + p * 8));
          s[n] = __builtin_amdgcn_mfma_f32_16x16x32_bf16(qf[kb], b, s[n], 0, 0, 0);
        }
      }
      // causal mask on diagonal chunk only (s already in exp2 domain)
      if (j == qt) {
        #pragma unroll
        for (int n = 0; n < 4; n++)
          #pragma unroll
          for (int i = 0; i < 4; i++) {
            int qr = 16 * w + quad * 4 + i;
            int kr = n * 16 + l16;
            if (kr > qr) s[n][i] = -1e30f;
          }
      }
      float mx[4];
      #pragma unroll
      for (int i = 0; i < 4; i++)
        mx[i] = fmaxf(fmaxf(s[0][i], s[1][i]), fmaxf(s[2][i], s[3][i]));
      #pragma unroll
      for (int off = 1; off < 16; off <<= 1)
        #pragma unroll
        for (int i = 0; i < 4; i++)
          mx[i] = fmaxf(mx[i], __shfl_xor(mx[i], off, 64));

      float alpha[4], rsum[4];
      #pragma unroll
      for (int i = 0; i < 4; i++) {
        float mn = fmaxf(m_i[i], mx[i]);
        alpha[i] = fast_exp2(m_i[i] - mn);
        m_i[i] = mn;
        rsum[i] = 0.0f;
      }
      #pragma unroll
      for (int n = 0; n < 4; n++)
        #pragma unroll
        for (int i = 0; i < 4; i++) {
          float p = fast_exp2(s[n][i] - m_i[i]);
          rsum[i] += p;
          int row = 16 * w + quad * 4 + i, col = n * 16 + l16;
          Ps[row * 72 + col] = f2bf(p);
        }
      #pragma unroll
      for (int off = 1; off < 16; off <<= 1)
        #pragma unroll
        for (int i = 0; i < 4; i++)
          rsum[i] += __shfl_xor(rsum[i], off, 64);
      #pragma unroll
      for (int i = 0; i < 4; i++) l_i[i] = l_i[i] * alpha[i] + rsum[i];
      #pragma unroll
      for (int n = 0; n < 8; n++)
        #pragma unroll
        for (int i = 0; i < 4; i++) zacc[n][i] *= alpha[i];

      // O += P V  (Ps rows are wave-private: compiler's lgkmcnt handles WAR)
      #pragma unroll
      for (int kk = 0; kk < 2; kk++) {
        bf16x8 af = as_frag(lds_ld16(Ps + (w * 16 + l16) * 72 + (kk * 4 + quad) * 8));
        #pragma unroll
        for (int n = 0; n < 8; n++) {
          int e = n * 16 + l16;
          int ug = kk * 4 + quad;
          int p = ug ^ (e & 7);
          bf16x8 b = as_frag(lds_ld16(VsC + e * 64 + p * 8));
          zacc[n] = __builtin_amdgcn_mfma_f32_16x16x32_bf16(af, b, zacc[n], 0, 0, 0);
        }
      }
      __syncthreads();   // reads of buf[cur] done; staging j+1 drained
    }

    // epilogue: Z[b*2048+pos][h*128+e] = zacc / l  (bf16)
    int b_ = bh >> 4, h = bh & 15;
    #pragma unroll
    for (int n = 0; n < 8; n++)
      #pragma unroll
      for (int i = 0; i < 4; i++) {
        int row = q0 + 16 * w + quad * 4 + i;
        int col = h * DHEAD + n * 16 + l16;
        Z[((size_t)(b_ * SEQ + row)) * DMODEL + col] = f2bf(zacc[n][i] / l_i[i]);
      }
  }
}

// ---------------------------------------------------------------------------
// Output projection (m97-style): out f32 = Z bf16 * WoT + bO
// ---------------------------------------------------------------------------
__global__ __launch_bounds__(256, 4) void gemm_out(
    const ushort* __restrict__ Zin, const ushort* __restrict__ WoT,
    const float* __restrict__ bO, float* __restrict__ out)
{
  int mt = blockIdx.x, ntile = blockIdx.y;
  __shared__ __align__(16) ushort As[128 * 64];
  __shared__ __align__(16) ushort Bs[128 * 64];
  int tid = threadIdx.x, lane = tid & 63, w = tid >> 6;
  int wm = w >> 1, wn = w & 1;
  int l16 = lane & 15, quad = lane >> 4;

  const ushort* Ag = Zin + (size_t)(mt * 128) * DMODEL;
  const ushort* Bg = WoT + (size_t)(ntile * 128) * DMODEL;

  int soff[4]; int sc[4];
  #pragma unroll
  for (int t = 0; t < 4; t++) {
    int c = w * 4 + t;
    int r = c * 8 + (lane >> 3);
    int p = lane & 7;
    int g = p ^ (r & 7);
    soff[t] = r * DMODEL + g * 8;
    sc[t] = c * 512;
  }

  f32x4 acc[4][4] = {};
  for (int k0 = 0; k0 < DMODEL; k0 += 64) {
    __syncthreads();
    #pragma unroll
    for (int t = 0; t < 4; t++) {
      async_cp16(Ag + soff[t] + k0, As + sc[t]);
      async_cp16(Bg + soff[t] + k0, Bs + sc[t]);
    }
    __syncthreads();
    #pragma unroll
    for (int kk = 0; kk < 2; kk++) {
      bf16x8 a[4], b[4];
      #pragma unroll
      for (int i = 0; i < 4; i++) {
        int row = wm * 64 + i * 16 + l16;
        int p = (kk * 4 + quad) ^ (l16 & 7);
        a[i] = as_frag(lds_ld16(As + row * 64 + p * 8));
      }
      #pragma unroll
      for (int i = 0; i < 4; i++) {
        int row = wn * 64 + i * 16 + l16;
        int p = (kk * 4 + quad) ^ (l16 & 7);
        b[i] = as_frag(lds_ld16(Bs + row * 64 + p * 8));
      }
      #pragma unroll
      for (int i = 0; i < 4; i++)
        #pragma unroll
        for (int j = 0; j < 4; j++)
          acc[i][j] = __builtin_amdgcn_mfma_f32_16x16x32_bf16(a[i], b[j], acc[i][j], 0, 0, 0);
    }
  }
  #pragma unroll
  for (int i = 0; i < 4; i++) {
    #pragma unroll
    for (int j = 0; j < 4; j++) {
      int col = ntile * 128 + wn * 64 + j * 16 + l16;
      float bb = bO[col];
      #pragma unroll
      for (int r = 0; r < 4; r++) {
        int row = mt * 128 + wm * 64 + i * 16 + quad * 4 + r;
        out[(size_t)row * DMODEL + col] = acc[i][j][r] + bb;
      }
    }
  }
}

// ---------------------------------------------------------------------------
extern "C" void kernel_launch(void* const* d_in, const int* in_sizes, int n_in,
                              void* d_out, int out_size, void* d_ws, size_t ws_size,
                              hipStream_t stream)
{
  const float* x  = (const float*)d_in[0];
  const float* Wq = (const float*)d_in[1];
  const float* Wk = (const float*)d_in[2];
  const float* Wv = (const float*)d_in[3];
  const float* Wo = (const float*)d_in[4];
  const float* bQ = (const float*)d_in[5];
  const float* bK = (const float*)d_in[6];
  const float* bV = (const float*)d_in[7];
  const float* bO = (const float*)d_in[8];
  float* out = (float*)d_out;

  ushort* ws = (ushort*)d_ws;
  const size_t WSZ = (size_t)NHEADS * DHEAD * DMODEL;       // 4,194,304
  const size_t QSZ = (size_t)BATCH * NHEADS * SEQ * DHEAD;  // 8,388,608
  ushort* xb  = ws;
  ushort* WqT = xb + (size_t)MROWS * DMODEL;
  ushort* WkT = WqT + WSZ;
  ushort* WvT = WkT + WSZ;
  ushort* WoT = WvT + WSZ;
  ushort* Qb  = WoT + (size_t)DMODEL * DMODEL;
  ushort* Kb  = Qb + QSZ;
  ushort* VtB = Kb + QSZ;
  ushort* Zb  = VtB + QSZ;

  dim3 tb(256);
  prep<<<dim3(18432), tb, 0, stream>>>(x, Wq, Wk, Wv, Wo,
                                       xb, WqT, WkT, WvT, WoT);

  gemm_qkv<<<dim3(32, 16, 3), tb, 0, stream>>>(xb, WqT, WkT, WvT, bQ, bK, bV,
                                               Qb, Kb, VtB);

  flash_attn<<<dim3(16, 32), tb, 0, stream>>>(Qb, Kb, VtB, Zb);

  gemm_out<<<dim3(32, 16), tb, 0, stream>>>(Zb, WoT, bO, out);
}